// Round 7
// baseline (656.301 us; speedup 1.0000x reference)
//
#include <hip/hip_runtime.h>

#define cN 16384
#define cE 65536
#define cT 2048
#define CAP 168

typedef __attribute__((ext_vector_type(8))) short short8;
typedef __attribute__((ext_vector_type(4))) float f32x4;
typedef __attribute__((ext_vector_type(4))) unsigned u32x4;

__device__ __forceinline__ short f2bf(float f){
  unsigned u = __float_as_uint(f);
  u = (u + 0x7FFFu + ((u >> 16) & 1u)) >> 16;
  return (short)u;
}
__device__ __forceinline__ float bf2f(short s){
  return __uint_as_float(((unsigned)(unsigned short)s) << 16);
}
__device__ __forceinline__ unsigned cvtpk(float lo, float hi){
  unsigned r;
  asm("v_cvt_pk_bf16_f32 %0, %1, %2" : "=v"(r) : "v"(lo), "v"(hi));
  return r;
}
__device__ __forceinline__ float sigm(float x){ return 1.f / (1.f + __expf(-x)); }
__device__ __forceinline__ float wred(float v){
  v += __shfl_xor(v, 32); v += __shfl_xor(v, 16); v += __shfl_xor(v, 8);
  v += __shfl_xor(v, 4);  v += __shfl_xor(v, 2);  v += __shfl_xor(v, 1);
  return v;
}
__device__ __forceinline__ float wredmax(float v){
  v = fmaxf(v, __shfl_xor(v, 32)); v = fmaxf(v, __shfl_xor(v, 16));
  v = fmaxf(v, __shfl_xor(v, 8));  v = fmaxf(v, __shfl_xor(v, 4));
  v = fmaxf(v, __shfl_xor(v, 2));  v = fmaxf(v, __shfl_xor(v, 1));
  return v;
}

// out = relu(x @ W_lin0.T + b)
__global__ __launch_bounds__(256) void k_lin0(const float* __restrict__ x,
    const float* __restrict__ W, const float* __restrict__ b, float* __restrict__ out)
{
  int i = blockIdx.x * 256 + threadIdx.x;       // cN*64
  int n = i >> 6, f = i & 63;
  float acc = b[f] + x[n*3]*W[f*3] + x[n*3+1]*W[f*3+1] + x[n*3+2]*W[f*3+2];
  out[i] = fmaxf(acc, 0.f);
}

// h1 = bf16(relu(edge_attr @ W_e1.T + b_e1))
__global__ __launch_bounds__(256) void k_h1(const float* __restrict__ ea,
    const float* __restrict__ W, const float* __restrict__ b, short* __restrict__ h1)
{
  int i = blockIdx.x * 256 + threadIdx.x;       // cE*128
  int e = i >> 7, k = i & 127;
  const float* a = ea + e * 7;
  const float* w = W + k * 7;
  float acc = b[k];
  #pragma unroll
  for (int c = 0; c < 7; c++) acc += a[c] * w[c];
  h1[i] = f2bf(fmaxf(acc, 0.f));
}

// W2 -> fragment-major bf16 layout, chunk-local k-major element order:
// col-in-chunk pos = ks*32 + kg*8 + j  <->  (k = ks*4 + kg, d = c*8 + j)
__global__ __launch_bounds__(256) void k_w2f(const float* __restrict__ W2, short* __restrict__ w2f)
{
  int o = blockIdx.x * 256 + threadIdx.x;       // 524288
  int j = o & 7, l = (o >> 3) & 63, ks = (o >> 9) & 31, c = (o >> 14) & 7, fb = (o >> 17) & 3;
  int f = fb * 16 + (l & 15);
  int d = c * 8 + j;
  int k = ks * 4 + ((l >> 4) & 3);
  w2f[o] = f2bf(W2[(d * 64 + f) * 128 + k]);
}

// b2 -> B-fragment layout for the bias MFMA (d = ks2*32 + kg*8 + j)
__global__ __launch_bounds__(256) void k_b2f(const float* __restrict__ b2, short* __restrict__ b2f)
{
  int o = blockIdx.x * 256 + threadIdx.x;       // 4096
  int j = o & 7, l = (o >> 3) & 63, ks2 = (o >> 9) & 1, fb = (o >> 10) & 3;
  int d = ks2 * 32 + ((l >> 4) & 3) * 8 + j;
  int f = fb * 16 + (l & 15);
  b2f[o] = f2bf(b2[d * 64 + f]);
}

// pack conv_root / gru_Wih / gru_Whh into B-fragment layout (28 col-blocks of 16)
__global__ __launch_bounds__(256) void k_wpack(const float* __restrict__ convW,
    const float* __restrict__ Wih, const float* __restrict__ Whh, short* __restrict__ wpk)
{
  int o = blockIdx.x * 256 + threadIdx.x;       // 28672
  int j = o & 7, l = (o >> 3) & 63, kc = (o >> 9) & 1, cb = o >> 10;
  int k = kc * 32 + ((l >> 4) & 3) * 8 + j;
  int c16 = l & 15;
  float v;
  if (cb < 4)       v = convW[k * 64 + cb * 16 + c16];
  else if (cb < 16) v = Wih[((cb - 4) * 16 + c16) * 64 + k];
  else              v = Whh[((cb - 16) * 16 + c16) * 64 + k];
  wpk[o] = f2bf(v);
}

__global__ __launch_bounds__(256) void k_deg(const int* __restrict__ ei, int* __restrict__ deg)
{
  int e = blockIdx.x * 256 + threadIdx.x;
  atomicAdd(&deg[ei[cE + e]], 1);
}

// exclusive scan over 16384 degrees; also fills cnt = max(deg,1)
__global__ __launch_bounds__(1024) void k_scan(const int* __restrict__ deg,
    int* __restrict__ rowp, float* __restrict__ cnt)
{
  __shared__ int part[1024];
  int tid = threadIdx.x;
  int base = tid * 16;
  int loc[16]; int s = 0;
  #pragma unroll
  for (int i = 0; i < 16; i++){ loc[i] = s; s += deg[base + i]; }
  part[tid] = s;
  __syncthreads();
  for (int off = 1; off < 1024; off <<= 1){
    int v = (tid >= off) ? part[tid - off] : 0;
    __syncthreads();
    part[tid] += v;
    __syncthreads();
  }
  int inc = part[tid];
  int eb = inc - s;
  #pragma unroll
  for (int i = 0; i < 16; i++){
    rowp[base + i] = eb + loc[i];
    int dv = deg[base + i];
    cnt[base + i] = (float)(dv > 0 ? dv : 1);
  }
  if (tid == 1023) rowp[16384] = inc;
}

__global__ __launch_bounds__(256) void k_scatter(const int* __restrict__ ei,
    const int* __restrict__ rowp, int* __restrict__ cur,
    int* __restrict__ esrc, int* __restrict__ eidx)
{
  int e = blockIdx.x * 256 + threadIdx.x;
  int t = ei[cE + e];
  int pos = rowp[t] + atomicAdd(&cur[t], 1);
  esrc[pos] = ei[e];
  eidx[pos] = e;
}

// Fused bilinear aggregation: 32 targets/block, 512 threads (8 waves -> 2 waves/SIMD).
// aggr[t,f] = sum_{d,k} S_t[d,k]*W2[(d,f),k] + sum_d os_t[d]*b2[d*64+f]
__global__ __launch_bounds__(512) void k_sagg(const float* __restrict__ out,
    const short* __restrict__ h1, const short* __restrict__ w2f,
    const short* __restrict__ b2f, const int* __restrict__ rowp,
    const int* __restrict__ esrc, const int* __restrict__ eidx,
    float* __restrict__ aggr)
{
  __shared__ __align__(16) short S[32][1040];       // chunk-local pos = k*8 + d
  __shared__ __align__(16) unsigned h1i[CAP][64];   // packed (h1[k=lane], h1[k=64+lane])
  __shared__ __align__(16) unsigned outsp[CAP][32]; // bf16-pair packed out rows
  __shared__ __align__(16) short osb[32][72];
  int tid = threadIdx.x, w = tid >> 6, lane = tid & 63;
  int t0 = blockIdx.x * 32;

  int ebase = rowp[t0];
  int eend  = rowp[t0 + 32];
  int ecnt  = eend - ebase;
  bool fits = (ecnt <= CAP);
  int scnt  = fits ? ecnt : CAP;
  // ---- stage edge data once (coalesced) ----
  for (int i = w; i < scnt; i += 8){
    int eid = eidx[ebase + i];
    int src = esrc[ebase + i];
    unsigned lo = (unsigned short)h1[(size_t)eid * 128 + lane];
    unsigned hi = (unsigned short)h1[(size_t)eid * 128 + 64 + lane];
    h1i[i][lane] = lo | (hi << 16);
    if (lane < 32){
      float2 v = *(const float2*)&out[(size_t)src * 64 + lane * 2];
      outsp[i][lane] = cvtpk(v.x, v.y);
    }
  }
  // per-wave target slices (4 targets per wave)
  int toff[4], tcnt[4];
  #pragma unroll
  for (int g = 0; g < 4; g++){
    int t = t0 + w * 4 + g;
    int a = rowp[t], b = rowp[t + 1];
    toff[g] = a - ebase; tcnt[g] = b - a;
  }
  __syncthreads();

  // ---- os_t[d] once (lane = d), bf16 into osb ----
  #pragma unroll
  for (int g = 0; g < 4; g++){
    int ti = w * 4 + g;
    float os = 0.f;
    int tf = toff[g], tc = tcnt[g];
    for (int p = 0; p < tc; p++){
      int slot = tf + p;
      if (slot < CAP){
        unsigned u = outsp[slot][lane >> 1];
        os += __uint_as_float((lane & 1) ? (u & 0xFFFF0000u) : (u << 16));
      } else {
        os += out[(size_t)esrc[ebase + slot] * 64 + lane];
      }
    }
    osb[ti][lane] = (short)cvtpk(os, os);
  }

  f32x4 acc = {0.f, 0.f, 0.f, 0.f};
  int arow = lane & 15, kg = lane >> 4;
  int rb = w >> 2, fb = w & 3;
  for (int c = 0; c < 8; ++c){
    // ---- phase A: accumulate S-slice (d = c*8 .. c*8+7; k = lane / 64+lane) ----
    #pragma unroll
    for (int g = 0; g < 4; ++g){
      int ti = w * 4 + g;
      float a0[8], a1[8];
      #pragma unroll
      for (int d = 0; d < 8; d++){ a0[d] = 0.f; a1[d] = 0.f; }
      int tc = tcnt[g], tf = toff[g];
      if (fits){
        #pragma unroll 2
        for (int p = 0; p < tc; ++p){
          int slot = tf + p;
          unsigned u = h1i[slot][lane];
          float h1a = __uint_as_float(u << 16);
          float h1b = __uint_as_float(u & 0xFFFF0000u);
          u32x4 ov = *(const u32x4*)&outsp[slot][c * 4];
          float o0 = __uint_as_float(ov[0] << 16), o1 = __uint_as_float(ov[0] & 0xFFFF0000u);
          float o2 = __uint_as_float(ov[1] << 16), o3 = __uint_as_float(ov[1] & 0xFFFF0000u);
          float o4 = __uint_as_float(ov[2] << 16), o5 = __uint_as_float(ov[2] & 0xFFFF0000u);
          float o6 = __uint_as_float(ov[3] << 16), o7 = __uint_as_float(ov[3] & 0xFFFF0000u);
          a0[0] = fmaf(o0, h1a, a0[0]); a1[0] = fmaf(o0, h1b, a1[0]);
          a0[1] = fmaf(o1, h1a, a0[1]); a1[1] = fmaf(o1, h1b, a1[1]);
          a0[2] = fmaf(o2, h1a, a0[2]); a1[2] = fmaf(o2, h1b, a1[2]);
          a0[3] = fmaf(o3, h1a, a0[3]); a1[3] = fmaf(o3, h1b, a1[3]);
          a0[4] = fmaf(o4, h1a, a0[4]); a1[4] = fmaf(o4, h1b, a1[4]);
          a0[5] = fmaf(o5, h1a, a0[5]); a1[5] = fmaf(o5, h1b, a1[5]);
          a0[6] = fmaf(o6, h1a, a0[6]); a1[6] = fmaf(o6, h1b, a1[6]);
          a0[7] = fmaf(o7, h1a, a0[7]); a1[7] = fmaf(o7, h1b, a1[7]);
        }
      } else {
        for (int p = 0; p < tc; ++p){
          int slot = tf + p;
          if (slot < CAP){
            unsigned u = h1i[slot][lane];
            float h1a = __uint_as_float(u << 16);
            float h1b = __uint_as_float(u & 0xFFFF0000u);
            u32x4 ov = *(const u32x4*)&outsp[slot][c * 4];
            #pragma unroll
            for (int d = 0; d < 4; d++){
              float lo = __uint_as_float(ov[d] << 16);
              float hi = __uint_as_float(ov[d] & 0xFFFF0000u);
              a0[2*d]   = fmaf(lo, h1a, a0[2*d]);   a1[2*d]   = fmaf(lo, h1b, a1[2*d]);
              a0[2*d+1] = fmaf(hi, h1a, a0[2*d+1]); a1[2*d+1] = fmaf(hi, h1b, a1[2*d+1]);
            }
          } else {
            int eid = eidx[ebase + slot];
            int src = esrc[ebase + slot];
            float h1a = bf2f(h1[(size_t)eid * 128 + lane]);
            float h1b = bf2f(h1[(size_t)eid * 128 + 64 + lane]);
            #pragma unroll
            for (int d = 0; d < 8; d++){
              float o = out[(size_t)src * 64 + c * 8 + d];
              a0[d] = fmaf(o, h1a, a0[d]); a1[d] = fmaf(o, h1b, a1[d]);
            }
          }
        }
      }
      // S writes: k-major pos = k*8+d; one b128 per k (k=lane and k=64+lane)
      u32x4 p0, p1;
      p0[0] = cvtpk(a0[0], a0[1]); p0[1] = cvtpk(a0[2], a0[3]);
      p0[2] = cvtpk(a0[4], a0[5]); p0[3] = cvtpk(a0[6], a0[7]);
      p1[0] = cvtpk(a1[0], a1[1]); p1[1] = cvtpk(a1[2], a1[3]);
      p1[2] = cvtpk(a1[4], a1[5]); p1[3] = cvtpk(a1[6], a1[7]);
      *(u32x4*)&S[ti][lane * 8]       = p0;
      *(u32x4*)&S[ti][512 + lane * 8] = p1;
    }
    __syncthreads();
    // ---- phase B: MFMA contraction for this chunk (1024 elements) ----
    const short* bbase = w2f + ((size_t)(fb * 8 + c) * 32) * 512 + lane * 8;
    #pragma unroll
    for (int ks = 0; ks < 32; ++ks){
      short8 afr = *(const short8*)&S[rb * 16 + arow][ks * 32 + kg * 8];
      short8 bfr = *(const short8*)(bbase + (size_t)ks * 512);
      acc = __builtin_amdgcn_mfma_f32_16x16x32_bf16(afr, bfr, acc, 0, 0, 0);
    }
    __syncthreads();
  }
  // ---- bias term as 2 MFMA steps: acc += os @ B2 ----
  #pragma unroll
  for (int ks2 = 0; ks2 < 2; ++ks2){
    short8 osf = *(const short8*)&osb[rb * 16 + arow][ks2 * 32 + kg * 8];
    short8 bfr = *(const short8*)(b2f + ((size_t)((fb * 2 + ks2) * 64 + lane)) * 8);
    acc = __builtin_amdgcn_mfma_f32_16x16x32_bf16(osf, bfr, acc, 0, 0, 0);
  }
  // ---- store raw sums ----
  int fcol = fb * 16 + arow;
  int trow = rb * 16 + kg * 4;
  #pragma unroll
  for (int q = 0; q < 4; q++)
    aggr[(size_t)(t0 + trow + q) * 64 + fcol] = acc[q];
}

// MFMA node update: m = relu(aggr/cnt + out@conv + cb); GRU(m, out) -> out.
__global__ __launch_bounds__(256) void k_nodeM(float* __restrict__ out,
    const float* __restrict__ aggr, const float* __restrict__ cnt,
    const short* __restrict__ wpk, const float* __restrict__ convB,
    const float* __restrict__ bih, const float* __restrict__ bhh)
{
  __shared__ __align__(16) short outA[64][72];
  __shared__ __align__(16) short mA[64][72];
  __shared__ float sb[448];
  const short8* WF = (const short8*)wpk;
  int tid = threadIdx.x, w = tid >> 6, lane = tid & 63;
  int n0 = blockIdx.x * 64;
  for (int i = tid; i < 2048; i += 256){
    int r = i >> 5, c2 = (i & 31) * 2;
    float2 v = *(const float2*)&out[(size_t)(n0 + r) * 64 + c2];
    *(unsigned*)&outA[r][c2] = cvtpk(v.x, v.y);
  }
  if (tid < 64) sb[tid] = convB[tid];
  for (int i = tid; i < 192; i += 256){ sb[64 + i] = bih[i]; sb[256 + i] = bhh[i]; }
  __syncthreads();
  int arow = lane & 15, kg = lane >> 4;
  int r0 = w * 16;
  short8 aof0 = *(const short8*)&outA[r0 + arow][kg * 8];
  short8 aof1 = *(const short8*)&outA[r0 + arow][32 + kg * 8];
  float ic[4];
  #pragma unroll
  for (int q = 0; q < 4; q++)
    ic[q] = 1.0f / fmaxf(cnt[n0 + r0 + kg * 4 + q], 1.0f);
  #pragma unroll
  for (int cf = 0; cf < 4; cf++){
    f32x4 a = {0.f, 0.f, 0.f, 0.f};
    a = __builtin_amdgcn_mfma_f32_16x16x32_bf16(aof0, WF[(cf * 2 + 0) * 64 + lane], a, 0, 0, 0);
    a = __builtin_amdgcn_mfma_f32_16x16x32_bf16(aof1, WF[(cf * 2 + 1) * 64 + lane], a, 0, 0, 0);
    int col = cf * 16 + arow;
    float cb_ = sb[col];
    #pragma unroll
    for (int q = 0; q < 4; q++){
      int r = n0 + r0 + kg * 4 + q;
      float m = fmaxf(aggr[(size_t)r * 64 + col] * ic[q] + a[q] + cb_, 0.f);
      mA[r0 + kg * 4 + q][col] = f2bf(m);
    }
  }
  __syncthreads();
  short8 amf0 = *(const short8*)&mA[r0 + arow][kg * 8];
  short8 amf1 = *(const short8*)&mA[r0 + arow][32 + kg * 8];
  #pragma unroll
  for (int co = 0; co < 4; co++){
    f32x4 gir = {0,0,0,0}, giz = {0,0,0,0}, gin = {0,0,0,0};
    f32x4 ghr = {0,0,0,0}, ghz = {0,0,0,0}, ghn = {0,0,0,0};
    gir = __builtin_amdgcn_mfma_f32_16x16x32_bf16(amf0, WF[((4  + co) * 2 + 0) * 64 + lane], gir, 0, 0, 0);
    gir = __builtin_amdgcn_mfma_f32_16x16x32_bf16(amf1, WF[((4  + co) * 2 + 1) * 64 + lane], gir, 0, 0, 0);
    giz = __builtin_amdgcn_mfma_f32_16x16x32_bf16(amf0, WF[((8  + co) * 2 + 0) * 64 + lane], giz, 0, 0, 0);
    giz = __builtin_amdgcn_mfma_f32_16x16x32_bf16(amf1, WF[((8  + co) * 2 + 1) * 64 + lane], giz, 0, 0, 0);
    gin = __builtin_amdgcn_mfma_f32_16x16x32_bf16(amf0, WF[((12 + co) * 2 + 0) * 64 + lane], gin, 0, 0, 0);
    gin = __builtin_amdgcn_mfma_f32_16x16x32_bf16(amf1, WF[((12 + co) * 2 + 1) * 64 + lane], gin, 0, 0, 0);
    ghr = __builtin_amdgcn_mfma_f32_16x16x32_bf16(aof0, WF[((16 + co) * 2 + 0) * 64 + lane], ghr, 0, 0, 0);
    ghr = __builtin_amdgcn_mfma_f32_16x16x32_bf16(aof1, WF[((16 + co) * 2 + 1) * 64 + lane], ghr, 0, 0, 0);
    ghz = __builtin_amdgcn_mfma_f32_16x16x32_bf16(aof0, WF[((20 + co) * 2 + 0) * 64 + lane], ghz, 0, 0, 0);
    ghz = __builtin_amdgcn_mfma_f32_16x16x32_bf16(aof1, WF[((20 + co) * 2 + 1) * 64 + lane], ghz, 0, 0, 0);
    ghn = __builtin_amdgcn_mfma_f32_16x16x32_bf16(aof0, WF[((24 + co) * 2 + 0) * 64 + lane], ghn, 0, 0, 0);
    ghn = __builtin_amdgcn_mfma_f32_16x16x32_bf16(aof1, WF[((24 + co) * 2 + 1) * 64 + lane], ghn, 0, 0, 0);
    int col = co * 16 + arow;
    float bir = sb[64 + col],  biz = sb[128 + col], bin_ = sb[192 + col];
    float bhr = sb[256 + col], bhz = sb[320 + col], bhn = sb[384 + col];
    #pragma unroll
    for (int q = 0; q < 4; q++){
      size_t r = (size_t)(n0 + r0 + kg * 4 + q);
      float rr = sigm(gir[q] + bir + ghr[q] + bhr);
      float zz = sigm(giz[q] + biz + ghz[q] + bhz);
      float nn = tanhf(gin[q] + bin_ + rr * (ghn[q] + bhn));
      float o = out[r * 64 + col];
      out[r * 64 + col] = (1.f - zz) * nn + zz * o;
    }
  }
}

// Fused Set2Set step: redundant LSTM + dots + flash-local softmax partials.
// Page p = scal + p*256: [0..63]=hs, [64..127]=cs, [128..191]=r_raw, [193]=esum.
__global__ __launch_bounds__(256) void k_dotsF(const float* __restrict__ out,
    const float* __restrict__ Wih, const float* __restrict__ Whh,
    const float* __restrict__ bih, const float* __restrict__ bhh,
    float* __restrict__ scal, float* __restrict__ rbuf,
    float* __restrict__ bmbuf, float* __restrict__ esbuf, int st)
{
  __shared__ float q[128];
  __shared__ float hsL[64];
  __shared__ float gsh[4][64];
  __shared__ float hsh[64];
  __shared__ float smax[4];
  __shared__ float otile[64][64];
  __shared__ float sarr[64];
  __shared__ float ebuf[64];
  __shared__ float rpart[4][64];
  const float* pg = scal + st * 256;
  float* pn = scal + (st + 1) * 256;
  int tid = threadIdx.x, gg = tid >> 6, lane = tid & 63;
  if (gg == 0){
    float hs = pg[lane];
    float es = pg[193];
    float rv = (es == 0.f) ? 0.f : pg[128 + lane] / es;
    q[lane] = hs; q[64 + lane] = rv; hsL[lane] = hs;
  }
  __syncthreads();
  float2 fq = *(const float2*)&q[2 * lane];
  float hv0 = hsL[lane];
  #pragma unroll 4
  for (int o = 0; o < 64; o++){
    int row = gg * 64 + o;
    float2 wv = *(const float2*)&Wih[(size_t)row * 128 + 2 * lane];
    float s = wv.x * fq.x + wv.y * fq.y + Whh[(size_t)row * 64 + lane] * hv0;
    s = wred(s);
    if (lane == 0) gsh[gg][o] = s;
  }
  __syncthreads();
  if (gg == 0){
    float gi = gsh[0][lane] + bih[lane]       + bhh[lane];
    float gf = gsh[1][lane] + bih[64 + lane]  + bhh[64 + lane];
    float gv = gsh[2][lane] + bih[128 + lane] + bhh[128 + lane];
    float go = gsh[3][lane] + bih[192 + lane] + bhh[192 + lane];
    float cs = pg[64 + lane];
    float cn = sigm(gf) * cs + sigm(gi) * tanhf(gv);
    float hn = sigm(go) * tanhf(cn);
    hsh[lane] = hn;
    if (blockIdx.x == 0){ pn[lane] = hn; pn[64 + lane] = cn; }
  }
  __syncthreads();
  int nbase = blockIdx.x * 64 + gg * 16;
  float hv = hsh[lane];
  float wmax = -3.4e38f;
  #pragma unroll 4
  for (int i = 0; i < 16; i++){
    float v = out[(size_t)(nbase + i) * 64 + lane];
    otile[gg * 16 + i][lane] = v;
    float p = wred(v * hv);
    if (lane == 0) sarr[gg * 16 + i] = p;
    wmax = fmaxf(wmax, p);
  }
  if (lane == 0) smax[gg] = wmax;
  __syncthreads();
  float bm = fmaxf(fmaxf(smax[0], smax[1]), fmaxf(smax[2], smax[3]));
  if (tid < 64) ebuf[tid] = __expf(sarr[tid] - bm);
  __syncthreads();
  float racc = 0.f;
  #pragma unroll 4
  for (int i = 0; i < 16; i++)
    racc += ebuf[gg * 16 + i] * otile[gg * 16 + i][lane];
  rpart[gg][lane] = racc;
  __syncthreads();
  if (gg == 0){
    float r = rpart[0][lane] + rpart[1][lane] + rpart[2][lane] + rpart[3][lane];
    rbuf[blockIdx.x * 64 + lane] = r;
  } else if (gg == 1){
    float es = wred(ebuf[lane]);
    if (lane == 0) esbuf[blockIdx.x] = es;
  } else if (gg == 2 && lane == 0) bmbuf[blockIdx.x] = bm;
}

// Global flash-combine (1 block). For st==2 also runs memory LSTM + value head.
__global__ __launch_bounds__(256) void k_smF(const float* __restrict__ rbuf,
    const float* __restrict__ bmbuf, const float* __restrict__ esbuf,
    float* __restrict__ scal, int st,
    const float* __restrict__ Wih, const float* __restrict__ Whh,
    const float* __restrict__ bih, const float* __restrict__ bhh,
    const float* __restrict__ hx, const float* __restrict__ cx,
    const float* __restrict__ W3, const float* __restrict__ b3,
    float* __restrict__ dout)
{
  __shared__ float redA[4], redB[4];
  __shared__ float rpart[4][64];
  __shared__ float rr[64];
  __shared__ float pool[128];
  __shared__ float hxs[64];
  __shared__ float gsh[4][64];
  __shared__ float lob[64];
  int tid = threadIdx.x, wid = tid >> 6, lane = tid & 63;
  float* pn = scal + (st + 1) * 256;
  float bm = bmbuf[tid];
  float m = wredmax(bm);
  if (lane == 0) redA[wid] = m;
  __syncthreads();
  float gmax = fmaxf(fmaxf(redA[0], redA[1]), fmaxf(redA[2], redA[3]));
  float ep = __expf(bm - gmax) * esbuf[tid];
  float es = wred(ep);
  if (lane == 0) redB[wid] = es;
  float racc = 0.f;
  for (int i = 0; i < 64; i++){
    int b = wid * 64 + i;
    racc += __expf(bmbuf[b] - gmax) * rbuf[b * 64 + lane];
  }
  rpart[wid][lane] = racc;
  __syncthreads();
  float esum = redB[0] + redB[1] + redB[2] + redB[3];
  if (wid == 0){
    float r = rpart[0][lane] + rpart[1][lane] + rpart[2][lane] + rpart[3][lane];
    rr[lane] = r;
    pn[128 + lane] = r;
  }
  if (tid == 0) pn[193] = esum;
  if (st == 2){
    __syncthreads();
    if (wid == 0){
      pool[lane] = pn[lane];               // hs3 (published by dotsF st2 block 0)
      pool[64 + lane] = rr[lane] / esum;   // final r
      hxs[lane] = hx[lane];
    }
    __syncthreads();
    float2 fq = *(const float2*)&pool[2 * lane];
    float hv = hxs[lane];
    #pragma unroll 4
    for (int o = 0; o < 64; o++){
      int row = wid * 64 + o;
      float2 wv = *(const float2*)&Wih[(size_t)row * 128 + 2 * lane];
      float s = wv.x * fq.x + wv.y * fq.y + Whh[(size_t)row * 64 + lane] * hv;
      s = wred(s);
      if (lane == 0) gsh[wid][o] = s;
    }
    __syncthreads();
    if (wid == 0){
      float gi = gsh[0][lane] + bih[lane]       + bhh[lane];
      float gf = gsh[1][lane] + bih[64 + lane]  + bhh[64 + lane];
      float gv = gsh[2][lane] + bih[128 + lane] + bhh[128 + lane];
      float go = gsh[3][lane] + bih[192 + lane] + bhh[192 + lane];
      float cn = sigm(gf) * cx[lane] + sigm(gi) * tanhf(gv);
      float hn = sigm(go) * tanhf(cn);
      dout[12289 + lane] = hn;
      dout[12353 + lane] = cn;
      scal[1024 + lane] = hn;
      lob[lane] = hn;
    }
    __syncthreads();
    if (wid == 0){
      float a = pool[lane] * W3[lane] + pool[64 + lane] * W3[64 + lane]
              + lob[lane] * W3[128 + lane];
      a = wred(a);
      if (lane == 0) dout[12288] = a + b3[0];
    }
  }
}

// torsion head. pf[t, j<256] = out[nr[j*32 + t/64], t%64]; pf[t, 256..319] = lstm_out[t>>5]
__global__ __launch_bounds__(256) void k_head(const float* __restrict__ out,
    const int* __restrict__ nr, const float* __restrict__ scal,
    const float* __restrict__ W1, const float* __restrict__ b1,
    const float* __restrict__ W2, const float* __restrict__ b2,
    float* __restrict__ dout)
{
  __shared__ float pf[4][320];
  __shared__ float hb[4][64];
  int tid = threadIdx.x, wid = tid >> 6, lane = tid & 63;
  int t = blockIdx.x * 4 + wid;
  float lo = scal[1024 + (t >> 5)];
  #pragma unroll
  for (int rep = 0; rep < 4; rep++){
    int j = rep * 64 + lane;
    int idx = nr[j * 32 + (t >> 6)];
    pf[wid][j] = out[idx * 64 + (t & 63)];
  }
  pf[wid][256 + lane] = lo;
  __syncthreads();
  float acc = b1[lane];
  const float* w = W1 + lane * 320;
  #pragma unroll 4
  for (int j = 0; j < 320; j++) acc += pf[wid][j] * w[j];
  hb[wid][lane] = fmaxf(acc, 0.f);
  __syncthreads();
  if (lane < 6){
    float a2 = b2[lane];
    const float* w2 = W2 + lane * 64;
    #pragma unroll 4
    for (int f = 0; f < 64; f++) a2 += hb[wid][f] * w2[f];
    dout[t * 6 + lane] = a2;
  }
}

extern "C" void kernel_launch(void* const* d_in, const int* in_sizes, int n_in,
                              void* d_out, int out_size, void* d_ws, size_t ws_size,
                              hipStream_t stream)
{
  const float* x         = (const float*)d_in[0];
  const float* edge_attr = (const float*)d_in[1];
  const int*   ei        = (const int*)d_in[2];
  const int*   nonring   = (const int*)d_in[3];
  const float* hx        = (const float*)d_in[4];
  const float* cx        = (const float*)d_in[5];
  const float* W_lin0 = (const float*)d_in[6];  const float* b_lin0 = (const float*)d_in[7];
  const float* W_e1   = (const float*)d_in[8];  const float* b_e1   = (const float*)d_in[9];
  const float* W_e2   = (const float*)d_in[10]; const float* b_e2   = (const float*)d_in[11];
  const float* convW  = (const float*)d_in[12]; const float* convB  = (const float*)d_in[13];
  const float* gWih   = (const float*)d_in[14]; const float* gWhh   = (const float*)d_in[15];
  const float* gbih   = (const float*)d_in[16]; const float* gbhh   = (const float*)d_in[17];
  const float* sWih   = (const float*)d_in[18]; const float* sWhh   = (const float*)d_in[19];
  const float* sbih   = (const float*)d_in[20]; const float* sbhh   = (const float*)d_in[21];
  const float* mWih   = (const float*)d_in[22]; const float* mWhh   = (const float*)d_in[23];
  const float* mbih   = (const float*)d_in[24]; const float* mbhh   = (const float*)d_in[25];
  const float* W_lin1 = (const float*)d_in[26]; const float* b_lin1 = (const float*)d_in[27];
  const float* W_lin2 = (const float*)d_in[28]; const float* b_lin2 = (const float*)d_in[29];
  const float* W_lin3 = (const float*)d_in[30]; const float* b_lin3 = (const float*)d_in[31];
  float* dout = (float*)d_out;

  char* w = (char*)d_ws;
  float* outb = (float*)w;  w += (size_t)cN * 64 * 4;
  float* aggr = (float*)w;  w += (size_t)cN * 64 * 4;
  short* h1   = (short*)w;  w += (size_t)cE * 128 * 2;
  short* w2f  = (short*)w;  w += (size_t)64 * 8192 * 2;
  short* b2f  = (short*)w;  w += 4096 * 2;
  short* wpk  = (short*)w;  w += 28672 * 2;
  float* cntb = (float*)w;  w += cN * 4;
  float* rbuf = (float*)w;  w += 256 * 64 * 4;
  float* bmbuf= (float*)w;  w += 256 * 4;
  float* esbuf= (float*)w;  w += 256 * 4;
  float* scal = (float*)w;  w += 1088 * 4;
  int* deg  = (int*)w;  w += cN * 4;
  int* cur  = (int*)w;  w += cN * 4;
  int* rowp = (int*)w;  w += (cN + 1) * 4 + 60;   // keep alignment
  int* esrc = (int*)w;  w += cE * 4;
  int* eidx = (int*)w;  w += cE * 4;

  hipMemsetAsync(deg, 0, cN * 4, stream);
  hipMemsetAsync(cur, 0, cN * 4, stream);
  hipMemsetAsync(scal, 0, 1088 * 4, stream);

  k_lin0<<<cN * 64 / 256, 256, 0, stream>>>(x, W_lin0, b_lin0, outb);
  k_h1<<<cE * 128 / 256, 256, 0, stream>>>(edge_attr, W_e1, b_e1, h1);
  k_w2f<<<64 * 8192 / 256, 256, 0, stream>>>(W_e2, w2f);
  k_b2f<<<16, 256, 0, stream>>>(b_e2, b2f);
  k_wpack<<<112, 256, 0, stream>>>(convW, gWih, gWhh, wpk);
  k_deg<<<cE / 256, 256, 0, stream>>>(ei, deg);
  k_scan<<<1, 1024, 0, stream>>>(deg, rowp, cntb);
  k_scatter<<<cE / 256, 256, 0, stream>>>(ei, rowp, cur, esrc, eidx);

  for (int it = 0; it < 3; it++){
    k_sagg<<<cN / 32, 512, 0, stream>>>(outb, h1, w2f, b2f, rowp, esrc, eidx, aggr);
    k_nodeM<<<cN / 64, 256, 0, stream>>>(outb, aggr, cntb, wpk, convB, gbih, gbhh);
  }

  for (int st = 0; st < 3; st++){
    k_dotsF<<<cN / 64, 256, 0, stream>>>(outb, sWih, sWhh, sbih, sbhh, scal, rbuf, bmbuf, esbuf, st);
    k_smF<<<1, 256, 0, stream>>>(rbuf, bmbuf, esbuf, scal, st,
                                 mWih, mWhh, mbih, mbhh, hx, cx, W_lin3, b_lin3, dout);
  }

  k_head<<<cT / 4, 256, 0, stream>>>(outb, nonring, scal, W_lin1, b_lin1, W_lin2, b_lin2, dout);
}